// Round 19
// baseline (417.707 us; speedup 1.0000x reference)
//
#include <hip/hip_runtime.h>
#include <math.h>

constexpr int BATCH = 4096;
constexpr int D_IN  = 784;
constexpr int F     = 512;
constexpr int NEC   = 512;   // codebook entries

constexpr int   GRID_N = 64;     // fq22 spatial grid
constexpr float GCELL  = 0.25f;  // covers [0,16) x [0,16)
constexpr int   GCAP   = 96;     // max candidates per cell

// ---------------- wave reduce helpers (no atomics) ----------------
__device__ __forceinline__ double wave_reduce_add(double v) {
    #pragma unroll
    for (int off = 32; off; off >>= 1) v += __shfl_xor(v, off);
    return v;
}

// 4-wave block: fixed-order fp64 partial -> pbuf[idx]
__device__ __forceinline__ void block_partial_idx(double dsum, double* pbuf, int idx) {
    __shared__ double wsum[4];
    const int t = threadIdx.x;
    dsum = wave_reduce_add(dsum);
    if ((t & 63) == 0) wsum[t >> 6] = dsum;
    __syncthreads();
    if (t == 0)
        pbuf[idx] = ((wsum[0] + wsum[1]) + wsum[2]) + wsum[3];
}

// ---------------- fused: fq22 grid build (blocks 0-1023) + weight-VQ (blocks 1024-1087) ----------------
// gridprep: one WAVE per cell; minUpper via shfl-fmin (order-independent ->
// identical thr); ordered list via ballot+prefix-popcount (ascending n ->
// bit-identical to serial scan). wq: round-4-exact dim-16 VQ body.
__global__ __launch_bounds__(256) void k_prep_wq(
    const float* __restrict__ E3, float* __restrict__ ecb3,
    int* __restrict__ gcnt, short* __restrict__ glist,
    const float* __restrict__ W2, const float* __restrict__ E2,
    float* __restrict__ qW2, double* __restrict__ pwq)
{
    const int t = threadIdx.x;
    if (blockIdx.x >= 1024) {
        // ---------- weight quantization (verbatim round-4 math) ----------
        const int wb = blockIdx.x - 1024;          // 0..63
        __shared__ float Es[NEC][16];
        __shared__ float Cn[NEC];
        for (int i = t; i < 16 * NEC; i += 256) Es[i & (NEC - 1)][i >> 9] = E2[i];
        __syncthreads();
        for (int n = t; n < NEC; n += 256) {
            float c = __fmul_rn(Es[n][0], Es[n][0]);
            #pragma unroll
            for (int j = 1; j < 16; ++j)
                c = __fadd_rn(c, __fmul_rn(Es[n][j], Es[n][j]));
            Cn[n] = c;
        }
        __syncthreads();
        const int idx = wb * 256 + t;              // 16384 vectors
        const int g = idx >> 6, c = idx & 63;
        float v[16];
        #pragma unroll
        for (int k = 0; k < 16; ++k)
            v[k] = W2[(size_t)(2 * g + (k & 1)) * F + 8 * c + (k >> 1)];
        float s[16];
        #pragma unroll
        for (int k = 0; k < 16; ++k) s[k] = __fmul_rn(v[k], v[k]);
        float r[8];
        #pragma unroll
        for (int j = 0; j < 8; ++j) r[j] = __fadd_rn(s[j], s[j + 8]);
        const float Aterm = __fadd_rn(
            __fadd_rn(__fadd_rn(r[0], r[1]), __fadd_rn(r[2], r[3])),
            __fadd_rn(__fadd_rn(r[4], r[5]), __fadd_rn(r[6], r[7])));
        float best = 3.4e38f; int bi = 0;
        for (int n = 0; n < NEC; ++n) {
            float bsum = __fmul_rn(v[0], Es[n][0]);
            #pragma unroll
            for (int k = 1; k < 16; ++k) bsum = fmaf(v[k], Es[n][k], bsum);
            float d = __fadd_rn(__fsub_rn(Aterm, __fadd_rn(bsum, bsum)), Cn[n]);
            if (d < best) { best = d; bi = n; }
        }
        double dsum = 0.0;
        #pragma unroll
        for (int k = 0; k < 16; ++k) {
            float df = __fsub_rn(Es[bi][k], v[k]);
            dsum += (double)df * (double)df;
            qW2[(size_t)(2 * g + (k & 1)) * F + 8 * c + (k >> 1)] = __fadd_rn(v[k], df);
        }
        block_partial_idx(dsum, pwq, wb);
        return;
    }
    // ---------- gridprep ----------
    __shared__ float ex[NEC], ey[NEC];
    for (int i = t; i < NEC; i += 256) {   // coalesced stage, once per block
        ex[i] = E3[i];
        ey[i] = E3[NEC + i];
    }
    __syncthreads();
    const int gid = blockIdx.x * 256 + t;
    if (gid < NEC) {   // pack {e0,e1,|e|^2,0} (blocks 0-1)
        float a0 = ex[gid], a1 = ey[gid];
        float cn = __fadd_rn(__fmul_rn(a0, a0), __fmul_rn(a1, a1));
        reinterpret_cast<float4*>(ecb3)[gid] = make_float4(a0, a1, cn, 0.f);
    }
    const int wv = t >> 6, l = t & 63;
    const int cell = blockIdx.x * 4 + wv;          // 4096 cells
    const int cx = cell & (GRID_N - 1), cy = cell >> 6;
    const float x0 = cx * GCELL, x1 = x0 + GCELL;
    const float y0 = cy * GCELL, y1 = y0 + GCELL;
    float mU = 3.4e38f;
    #pragma unroll
    for (int j = 0; j < 8; ++j) {
        const int n = j * 64 + l;
        float exn = ex[n], eyn = ey[n];
        float dxmax = fmaxf(x1 - exn, exn - x0);
        float dymax = fmaxf(y1 - eyn, eyn - y0);
        mU = fminf(mU, dxmax * dxmax + dymax * dymax);
    }
    #pragma unroll
    for (int off = 32; off; off >>= 1) mU = fminf(mU, __shfl_xor(mU, off));
    const float thr = mU + 0.01f;
    int cnt = 0;
    short* lst = glist + (size_t)cell * GCAP;
    #pragma unroll
    for (int j = 0; j < 8; ++j) {
        const int n = j * 64 + l;
        float exn = ex[n], eyn = ey[n];
        float dxmin = fmaxf(fmaxf(x0 - exn, exn - x1), 0.f);
        float dymin = fmaxf(fmaxf(y0 - eyn, eyn - y1), 0.f);
        const bool acc = (dxmin * dxmin + dymin * dymin <= thr);
        unsigned long long mask = __ballot(acc);
        if (acc) {
            int pos = cnt + __popcll(mask & ((1ull << l) - 1ull));
            if (pos < GCAP) lst[pos] = (short)n;
        }
        cnt += __popcll(mask);
    }
    if (l == 0) gcnt[cell] = cnt;
}

// ---- GEMM (NT) emulating BLAS sgemm: per-output sequential-k fma chain within
// ---- KC-panels, panel partials combined in order with fp32 adds (bit-exact).
// ---- 64x64 tile, 128 threads, 8x4/thread (1.5 B LDS per fma vs 2.0 at 4x4),
// ---- LDS dbuf + reg prefetch, XCD-bijective swizzle, 2 blocks/CU.
template<bool RELU, bool BN>
__global__ __launch_bounds__(128, 2) void k_gemm_np(
    const float* __restrict__ A, const float* __restrict__ Bw, float* __restrict__ C,
    int M, int N, int K, int KC,
    const float* __restrict__ mu, const float* __restrict__ rs,
    const float* __restrict__ gamma, const float* __restrict__ beta)
{
    __shared__ float As[2][16][68];
    __shared__ float Bs[2][16][68];
    const int t  = threadIdx.x;
    // XCD-bijective swizzle (nwg = 8*gridDim.y): XCD k owns 8 consecutive
    // A-panels x all bn -> per-XCD L2 reuse.
    const int nwgy = gridDim.y;
    const int bid  = blockIdx.y * 8 + blockIdx.x;
    const int swz  = (bid & 7) * nwgy + (bid >> 3);
    const int bm = (swz >> 3) * 64, bn = (swz & 7) * 64;
    const int tm = (t >> 4) * 8, tn = (t & 15) * 4;   // 8 rows x 4 cols / thread
    const int rA = t >> 1;               // 0..63: tile row to stage
    const int c8 = (t & 1) * 8;          // 0 or 8: k offset (8 floats/thread)
    const float* Arow = A + (size_t)(bm + rA) * K + c8;
    const float* Brow = Bw + (size_t)(bn + rA) * K + c8;

    float tot[8][4];
    float accp[8][4] = {};
    bool first = true;

#define GEMM_BNX(val, kidx)                                   \
    if (BN) {                                                 \
        float d_ = __fsub_rn(val, mu[kidx]);                  \
        d_ = __fmul_rn(d_, rs[kidx]);                         \
        d_ = __fmul_rn(d_, gamma[kidx]);                      \
        val = __fadd_rn(d_, beta[kidx]);                      \
    }

    // stage chunk 0
    {
        float4 a0 = *reinterpret_cast<const float4*>(Arow);
        float4 a1 = *reinterpret_cast<const float4*>(Arow + 4);
        float4 b0 = *reinterpret_cast<const float4*>(Brow);
        float4 b1 = *reinterpret_cast<const float4*>(Brow + 4);
        float av[8] = {a0.x, a0.y, a0.z, a0.w, a1.x, a1.y, a1.z, a1.w};
        float bv[8] = {b0.x, b0.y, b0.z, b0.w, b1.x, b1.y, b1.z, b1.w};
        #pragma unroll
        for (int e = 0; e < 8; ++e) {
            GEMM_BNX(av[e], c8 + e)
            As[0][c8 + e][rA] = av[e];
            Bs[0][c8 + e][rA] = bv[e];
        }
    }
    __syncthreads();

    int cur = 0;
    for (int k0 = 0; k0 < K; k0 += 16) {
        const bool has_next = (k0 + 16) < K;
        float4 a0p, a1p, b0p, b1p;
        if (has_next) {                     // issue next-chunk loads early
            a0p = *reinterpret_cast<const float4*>(Arow + k0 + 16);
            a1p = *reinterpret_cast<const float4*>(Arow + k0 + 20);
            b0p = *reinterpret_cast<const float4*>(Brow + k0 + 16);
            b1p = *reinterpret_cast<const float4*>(Brow + k0 + 20);
        }
        #pragma unroll
        for (int kk = 0; kk < 16; ++kk) {
            float4 alo = *reinterpret_cast<const float4*>(&As[cur][kk][tm]);
            float4 ahi = *reinterpret_cast<const float4*>(&As[cur][kk][tm + 4]);
            float4 b4  = *reinterpret_cast<const float4*>(&Bs[cur][kk][tn]);
            float aa[8] = {alo.x, alo.y, alo.z, alo.w, ahi.x, ahi.y, ahi.z, ahi.w};
            float bb[4] = {b4.x, b4.y, b4.z, b4.w};
            #pragma unroll
            for (int i = 0; i < 8; ++i)
                #pragma unroll
                for (int j = 0; j < 4; ++j)
                    accp[i][j] = fmaf(aa[i], bb[j], accp[i][j]);
        }
        if (has_next) {
            float av[8] = {a0p.x, a0p.y, a0p.z, a0p.w, a1p.x, a1p.y, a1p.z, a1p.w};
            float bv[8] = {b0p.x, b0p.y, b0p.z, b0p.w, b1p.x, b1p.y, b1p.z, b1p.w};
            const int alt = cur ^ 1;
            #pragma unroll
            for (int e = 0; e < 8; ++e) {
                GEMM_BNX(av[e], k0 + 16 + c8 + e)
                As[alt][c8 + e][rA] = av[e];
                Bs[alt][c8 + e][rA] = bv[e];
            }
        }
        __syncthreads();                    // single barrier per chunk
        const int kend = k0 + 16;
        if ((kend % KC) == 0 || kend == K) {   // panel boundary: fold partial
            #pragma unroll
            for (int i = 0; i < 8; ++i)
                #pragma unroll
                for (int j = 0; j < 4; ++j) {
                    tot[i][j] = first ? accp[i][j] : __fadd_rn(tot[i][j], accp[i][j]);
                    accp[i][j] = 0.f;
                }
            first = false;
        }
        cur ^= 1;
    }
#undef GEMM_BNX
    #pragma unroll
    for (int i = 0; i < 8; ++i) {
        float4 r;
        r.x = RELU ? fmaxf(tot[i][0], 0.f) : tot[i][0];
        r.y = RELU ? fmaxf(tot[i][1], 0.f) : tot[i][1];
        r.z = RELU ? fmaxf(tot[i][2], 0.f) : tot[i][2];
        r.w = RELU ? fmaxf(tot[i][3], 0.f) : tot[i][3];
        *reinterpret_cast<float4*>(&C[(size_t)(bm + tm + i) * N + bn + tn]) = r;
    }
}

// ---------------- fq21: dim-8 VQ, LDS codebook, index-only tracking ----------------
__global__ __launch_bounds__(256) void k_fq21_np(
    const float* __restrict__ h, const float* __restrict__ E,
    float* __restrict__ qx, double* __restrict__ pbuf)
{
    __shared__ float Es[NEC][8];
    __shared__ float Cn[NEC];
    const int t = threadIdx.x;
    for (int i = t; i < 8 * NEC; i += 256) Es[i & (NEC - 1)][i >> 9] = E[i];
    __syncthreads();
    for (int n = t; n < NEC; n += 256) {
        float c = __fmul_rn(Es[n][0], Es[n][0]);
        #pragma unroll
        for (int j = 1; j < 8; ++j)
            c = __fadd_rn(c, __fmul_rn(Es[n][j], Es[n][j]));
        Cn[n] = c;
    }
    __syncthreads();
    const int idx = blockIdx.x * 256 + t;
    const int b = idx >> 6, c = idx & 63;
    const float* hb = h + (size_t)b * F + c;
    float v[8];
    #pragma unroll
    for (int j = 0; j < 8; ++j) v[j] = hb[j * 64];
    float s[8];
    #pragma unroll
    for (int j = 0; j < 8; ++j) s[j] = __fmul_rn(v[j], v[j]);
    // numpy pairwise n=8: ((s0+s1)+(s2+s3)) + ((s4+s5)+(s6+s7))
    const float Aterm = __fadd_rn(
        __fadd_rn(__fadd_rn(s[0], s[1]), __fadd_rn(s[2], s[3])),
        __fadd_rn(__fadd_rn(s[4], s[5]), __fadd_rn(s[6], s[7])));
    float best = 3.4e38f; int bi = 0;
    for (int n = 0; n < NEC; ++n) {
        float4 e0 = *reinterpret_cast<const float4*>(&Es[n][0]);
        float4 e1 = *reinterpret_cast<const float4*>(&Es[n][4]);
        float bsum = __fmul_rn(v[0], e0.x);
        bsum = fmaf(v[1], e0.y, bsum);
        bsum = fmaf(v[2], e0.z, bsum);
        bsum = fmaf(v[3], e0.w, bsum);
        bsum = fmaf(v[4], e1.x, bsum);
        bsum = fmaf(v[5], e1.y, bsum);
        bsum = fmaf(v[6], e1.z, bsum);
        bsum = fmaf(v[7], e1.w, bsum);
        float d = __fadd_rn(__fsub_rn(Aterm, __fadd_rn(bsum, bsum)), Cn[n]);
        if (d < best) { best = d; bi = n; }
    }
    float4 q0 = *reinterpret_cast<const float4*>(&Es[bi][0]);
    float4 q1 = *reinterpret_cast<const float4*>(&Es[bi][4]);
    float bq[8] = {q0.x, q0.y, q0.z, q0.w, q1.x, q1.y, q1.z, q1.w};
    double dsum = 0.0;
    float* qb = qx + (size_t)b * F + c;
    #pragma unroll
    for (int j = 0; j < 8; ++j) {
        float df = __fsub_rn(bq[j], v[j]);        // fl(q - x)
        dsum += (double)df * (double)df;
        qb[j * 64] = __fadd_rn(v[j], df);         // fl(x + fl(q - x))
    }
    block_partial_idx(dsum, pbuf, blockIdx.x);
}

// ---------------- transpose qx [4096][512] -> qxT [512][4096] ----------------
__global__ __launch_bounds__(256) void k_transpose(
    const float* __restrict__ qx, float* __restrict__ qxT)
{
    __shared__ float tile[64][65];
    const int t = threadIdx.x;
    const int bx = blockIdx.x * 64;   // f base
    const int by = blockIdx.y * 64;   // b base
    const int r = t >> 4, c4 = (t & 15) * 4;
    #pragma unroll
    for (int s = 0; s < 4; ++s) {
        float4 v = *reinterpret_cast<const float4*>(&qx[(size_t)(by + r + s * 16) * F + bx + c4]);
        tile[r + s * 16][c4 + 0] = v.x; tile[r + s * 16][c4 + 1] = v.y;
        tile[r + s * 16][c4 + 2] = v.z; tile[r + s * 16][c4 + 3] = v.w;
    }
    __syncthreads();
    const int fo = t >> 4, b4 = (t & 15) * 4;
    #pragma unroll
    for (int s = 0; s < 4; ++s) {
        float4 v;
        v.x = tile[b4 + 0][fo + s * 16];
        v.y = tile[b4 + 1][fo + s * 16];
        v.z = tile[b4 + 2][fo + s * 16];
        v.w = tile[b4 + 3][fo + s * 16];
        *reinterpret_cast<float4*>(&qxT[(size_t)(bx + fo + s * 16) * BATCH + by + b4]) = v;
    }
}

// ---------------- BN stats: numpy sequential fp32 on contiguous qxT rows ----------------
// 32 blocks x 16 ACTIVE lanes (one column each, chains unchanged): spreads the
// uncoalesced TA request stream over 32 CUs and 4x's aggregate in-flight loads.
__global__ __launch_bounds__(64) void k_bn(
    const float* __restrict__ qxT, float* __restrict__ mu, float* __restrict__ rs)
{
    const int t = threadIdx.x;
    if (t >= 16) return;                       // 16 active lanes per wave
    const int f = blockIdx.x * 16 + t;         // 32 blocks x 16 = 512 cols
    const float4* rp = reinterpret_cast<const float4*>(qxT + (size_t)f * BATCH);

    float4 b0[4], b1[4], b2[4], b3[4], b4[4], b5[4], b6[4], b7[4];

#define BN_LD(B, c)                                                          \
    { _Pragma("unroll") for (int q = 0; q < 4; ++q) B[q] = rp[(c) * 4 + q]; }
#define BN_SUM(B)                                                            \
    { _Pragma("unroll") for (int q = 0; q < 4; ++q) {                        \
        acc = __fadd_rn(acc, B[q].x); acc = __fadd_rn(acc, B[q].y);          \
        acc = __fadd_rn(acc, B[q].z); acc = __fadd_rn(acc, B[q].w); } }
#define BN_VAR(B)                                                            \
    { _Pragma("unroll") for (int q = 0; q < 4; ++q) { float d_;              \
        d_ = __fsub_rn(B[q].x, m); acc2 = __fadd_rn(acc2, __fmul_rn(d_, d_));\
        d_ = __fsub_rn(B[q].y, m); acc2 = __fadd_rn(acc2, __fmul_rn(d_, d_));\
        d_ = __fsub_rn(B[q].z, m); acc2 = __fadd_rn(acc2, __fmul_rn(d_, d_));\
        d_ = __fsub_rn(B[q].w, m); acc2 = __fadd_rn(acc2, __fmul_rn(d_, d_)); } }

    // ---------- pass 1: mean (chunks of 16 rows; 256 chunks) ----------
    float acc = 0.f;
    BN_LD(b0, 0) BN_LD(b1, 1) BN_LD(b2, 2) BN_LD(b3, 3)
    BN_LD(b4, 4) BN_LD(b5, 5) BN_LD(b6, 6)
    for (int g = 0; g < 31; ++g) {
        BN_LD(b7, 8 * g + 7)  BN_SUM(b0)
        BN_LD(b0, 8 * g + 8)  BN_SUM(b1)
        BN_LD(b1, 8 * g + 9)  BN_SUM(b2)
        BN_LD(b2, 8 * g + 10) BN_SUM(b3)
        BN_LD(b3, 8 * g + 11) BN_SUM(b4)
        BN_LD(b4, 8 * g + 12) BN_SUM(b5)
        BN_LD(b5, 8 * g + 13) BN_SUM(b6)
        BN_LD(b6, 8 * g + 14) BN_SUM(b7)
    }
    BN_LD(b7, 255)
    BN_SUM(b0) BN_SUM(b1) BN_SUM(b2) BN_SUM(b3)
    BN_SUM(b4) BN_SUM(b5) BN_SUM(b6) BN_SUM(b7)
    const float m = __fmul_rn(acc, 1.f / 4096.f);   // exact (/2^12)

    // ---------- pass 2: biased var, numpy order ----------
    float acc2 = 0.f;
    BN_LD(b0, 0) BN_LD(b1, 1) BN_LD(b2, 2) BN_LD(b3, 3)
    BN_LD(b4, 4) BN_LD(b5, 5) BN_LD(b6, 6)
    for (int g = 0; g < 31; ++g) {
        BN_LD(b7, 8 * g + 7)  BN_VAR(b0)
        BN_LD(b0, 8 * g + 8)  BN_VAR(b1)
        BN_LD(b1, 8 * g + 9)  BN_VAR(b2)
        BN_LD(b2, 8 * g + 10) BN_VAR(b3)
        BN_LD(b3, 8 * g + 11) BN_VAR(b4)
        BN_LD(b4, 8 * g + 12) BN_VAR(b5)
        BN_LD(b5, 8 * g + 13) BN_VAR(b6)
        BN_LD(b6, 8 * g + 14) BN_VAR(b7)
    }
    BN_LD(b7, 255)
    BN_VAR(b0) BN_VAR(b1) BN_VAR(b2) BN_VAR(b3)
    BN_VAR(b4) BN_VAR(b5) BN_VAR(b6) BN_VAR(b7)
#undef BN_LD
#undef BN_SUM
#undef BN_VAR
    float var = __fmul_rn(acc2, 1.f / 4096.f);
    float w = __fadd_rn(var, 1e-5f);
    mu[f] = m;
    rs[f] = __fdiv_rn(1.0f, __fsqrt_rn(w));
}

// ---------------- fq22: dim-2 VQ via spatial-grid pruned search ----------------
__global__ __launch_bounds__(256) void k_fq22_np(
    const float* __restrict__ h2, const float* __restrict__ ecb3,
    const int* __restrict__ gcnt, const short* __restrict__ glist,
    float* __restrict__ qx2, double* __restrict__ pbuf)
{
    __shared__ float4 EsL[NEC];
    const int t = threadIdx.x;
    for (int n = t; n < NEC; n += 256)
        EsL[n] = reinterpret_cast<const float4*>(ecb3)[n];
    __syncthreads();
    const int b = blockIdx.x;
    const float v0 = h2[(size_t)b * F + t];         // >= 0 (relu)
    const float v1 = h2[(size_t)b * F + 256 + t];   // >= 0
    const float Aterm = __fadd_rn(__fmul_rn(v0, v0), __fmul_rn(v1, v1));
    float best = 3.4e38f; int bi = 0;
    const bool inbox = (v0 < 16.f) && (v1 < 16.f);
    int cx = (int)(v0 * 4.f), cy = (int)(v1 * 4.f);
    int cell = (cy << 6) + cx;
    int cnt = inbox ? gcnt[cell] : (NEC + 1);       // out-of-box -> full scan
    if (cnt <= GCAP) {
        const short* lst = glist + (size_t)cell * GCAP;
        int i = 0;
        const int cnt4 = cnt & ~3;
        for (; i < cnt4; i += 4) {                   // one 8B gather per 4 ids
            ushort4 ids = *reinterpret_cast<const ushort4*>(lst + i);
            float4 ea = EsL[ids.x];
            float4 eb = EsL[ids.y];
            float4 ec = EsL[ids.z];
            float4 ed = EsL[ids.w];
            float ba = fmaf(v1, ea.y, __fmul_rn(v0, ea.x));
            float da = __fadd_rn(__fsub_rn(Aterm, __fadd_rn(ba, ba)), ea.z);
            if (da < best) { best = da; bi = ids.x; }
            float bb = fmaf(v1, eb.y, __fmul_rn(v0, eb.x));
            float db = __fadd_rn(__fsub_rn(Aterm, __fadd_rn(bb, bb)), eb.z);
            if (db < best) { best = db; bi = ids.y; }
            float bc = fmaf(v1, ec.y, __fmul_rn(v0, ec.x));
            float dc = __fadd_rn(__fsub_rn(Aterm, __fadd_rn(bc, bc)), ec.z);
            if (dc < best) { best = dc; bi = ids.z; }
            float bd = fmaf(v1, ed.y, __fmul_rn(v0, ed.x));
            float dd = __fadd_rn(__fsub_rn(Aterm, __fadd_rn(bd, bd)), ed.z);
            if (dd < best) { best = dd; bi = ids.w; }
        }
        for (; i < cnt; ++i) {
            int id = lst[i];
            float4 e = EsL[id];
            float bsum = fmaf(v1, e.y, __fmul_rn(v0, e.x));
            float d = __fadd_rn(__fsub_rn(Aterm, __fadd_rn(bsum, bsum)), e.z);
            if (d < best) { best = d; bi = id; }
        }
    } else {
        for (int n = 0; n < NEC; ++n) {
            float4 e = EsL[n];
            float bsum = fmaf(v1, e.y, __fmul_rn(v0, e.x));
            float d = __fadd_rn(__fsub_rn(Aterm, __fadd_rn(bsum, bsum)), e.z);
            if (d < best) { best = d; bi = n; }
        }
    }
    float4 eb = EsL[bi];
    float d0 = __fsub_rn(eb.x, v0), d1 = __fsub_rn(eb.y, v1);
    qx2[(size_t)b * F + t]       = __fadd_rn(v0, d0);
    qx2[(size_t)b * F + 256 + t] = __fadd_rn(v1, d1);
    block_partial_idx((double)d0 * d0 + (double)d1 * d1, pbuf, blockIdx.x);
}

// ---------------- final thin GEMM + fused diff reduction ----------------
// blocks 0..1023: out[b,o] = sum_i qx2[b,i] * W3[o,i]; last block: reduce diffs.
__global__ __launch_bounds__(256) void k_gemm3(
    const float* __restrict__ qx2, const float* __restrict__ W3, float* __restrict__ out,
    const double* __restrict__ p21, const double* __restrict__ pwq,
    const double* __restrict__ p22)
{
    const int t = threadIdx.x;
    if (blockIdx.x == gridDim.x - 1) {
        __shared__ double sd[256];
        __shared__ double res[2];
        // --- p21 (1024) ---
        double s = 0.0;
        for (int i = t; i < 1024; i += 256) s += p21[i];
        sd[t] = s; __syncthreads();
        for (int o = 128; o; o >>= 1) { if (t < o) sd[t] += sd[t + o]; __syncthreads(); }
        if (t == 0) res[0] = sd[0];
        __syncthreads();
        // --- pwq (64) ---
        s = (t < 64) ? pwq[t] : 0.0;
        sd[t] = s; __syncthreads();
        for (int o = 128; o; o >>= 1) { if (t < o) sd[t] += sd[t + o]; __syncthreads(); }
        if (t == 0) res[1] = sd[0];
        __syncthreads();
        // --- p22 (4096) ---
        s = 0.0;
        for (int i = t; i < 4096; i += 256) s += p22[i];
        sd[t] = s; __syncthreads();
        for (int o = 128; o; o >>= 1) { if (t < o) sd[t] += sd[t + o]; __syncthreads(); }
        if (t == 0) {
            double d21 = res[0] * (1.0 / 2097152.0);   // 4096*64*8
            double dq  = res[1] * (1.0 / 262144.0);    // 256*64*16
            double d22 = sd[0]  * (1.0 / 2097152.0);   // 4096*256*2
            out[BATCH * 10] = (float)((d21 + d22) + dq);
        }
        return;
    }
    __shared__ float Ws[10 * F];
    for (int i = t; i < 10 * F; i += 256) Ws[i] = W3[i];
    __syncthreads();
    const int w = t >> 6, l = t & 63;
    const int b = blockIdx.x * 4 + w;
    const float* xb = qx2 + (size_t)b * F;
    double acc[10] = {};
    for (int i = l; i < F; i += 64) {
        double xv = (double)xb[i];
        #pragma unroll
        for (int o = 0; o < 10; ++o) acc[o] = fma(xv, (double)Ws[o * F + i], acc[o]);
    }
    #pragma unroll
    for (int o = 0; o < 10; ++o) {
        double a = wave_reduce_add(acc[o]);
        if (l == 0) out[(size_t)b * 10 + o] = (float)a;
    }
}

extern "C" void kernel_launch(void* const* d_in, const int* in_sizes, int n_in,
                              void* d_out, int out_size, void* d_ws, size_t ws_size,
                              hipStream_t stream)
{
    const float* x     = (const float*)d_in[0];
    const float* W1    = (const float*)d_in[1];
    const float* W2    = (const float*)d_in[2];
    const float* W3    = (const float*)d_in[3];
    const float* gamma = (const float*)d_in[4];
    const float* beta  = (const float*)d_in[5];
    const float* E1    = (const float*)d_in[6];   // [8,512]
    const float* E2    = (const float*)d_in[7];   // [16,512]
    const float* E3    = (const float*)d_in[8];   // [2,512]
    float* out = (float*)d_out;

    const int KC = 512;   // confirmed round 4 (BLIS/zen single-panel for K=512)

    char* ws = (char*)d_ws;
    float*  hf    = (float*)ws;                                 // 8 MB (h, then h2)
    float*  qxf   = (float*)(ws + (size_t) 8 * 1024 * 1024);    // 8 MB (qx, then qx2)
    float*  qW2f  = (float*)(ws + (size_t)16 * 1024 * 1024);    // 1 MB
    float*  muf   = (float*)(ws + (size_t)17 * 1024 * 1024);    // 512 f32
    float*  rsf   = muf + F;                                    // 512 f32
    float*  ecb3  = (float*)(ws + (size_t)17 * 1024 * 1024 + 8192);    // 512*4 f32
    int*    gcnt  = (int*)(ws + (size_t)18 * 1024 * 1024);      // 4096 int
    short*  glist = (short*)(ws + (size_t)18 * 1024 * 1024 + 16384);   // 4096*96 i16
    double* p21   = (double*)(ws + (size_t)19 * 1024 * 1024);   // 1024 f64
    double* pwq   = p21 + 1024;                                 // 64 f64
    double* p22   = pwq + 64;                                   // 4096 f64
    float*  qxT   = (float*)(ws + (size_t)20 * 1024 * 1024);    // 8 MB [512][4096]

    // gridprep (blocks 0-1023) + weight-VQ (blocks 1024-1087), one launch
    k_prep_wq<<<1088, 256, 0, stream>>>(E3, ecb3, gcnt, glist, W2, E2, qW2f, pwq);
    // h = relu(x @ W1^T)  — sgemm emulation, KC panels (784 = 512 + 272)
    k_gemm_np<true, false><<<dim3(F / 64, BATCH / 64), 128, 0, stream>>>(
        x, W1, hf, BATCH, F, D_IN, KC, nullptr, nullptr, nullptr, nullptr);
    // fq21 -> qx
    k_fq21_np<<<BATCH * 64 / 256, 256, 0, stream>>>(hf, E1, qxf, p21);
    // qx -> qxT (for contiguous column reads in k_bn)
    k_transpose<<<dim3(F / 64, BATCH / 64), 256, 0, stream>>>(qxf, qxT);
    // BN stats (sequential fp32, numpy order; 32-block/16-lane float4 pipeline)
    k_bn<<<32, 64, 0, stream>>>(qxT, muf, rsf);
    // h2 = relu(bn(qx) @ qW2^T) — K=512 = single panel -> pure sequential fma
    k_gemm_np<true, true><<<dim3(F / 64, BATCH / 64), 128, 0, stream>>>(
        qxf, qW2f, hf, BATCH, F, F, KC, muf, rsf, gamma, beta);
    // fq22 -> qx2 (grid-pruned, vectorized id gather)
    k_fq22_np<<<BATCH, 256, 0, stream>>>(hf, ecb3, gcnt, glist, qxf, p22);
    // out = qx2 @ W3^T (+ fused diff reduce in the extra block)
    k_gemm3<<<BATCH / 4 + 1, 256, 0, stream>>>(qxf, W3, out, p21, pwq, p22);
}

// Round 20
// 283.002 us; speedup vs baseline: 1.4760x; 1.4760x over previous
//
#include <hip/hip_runtime.h>
#include <math.h>

constexpr int BATCH = 4096;
constexpr int D_IN  = 784;
constexpr int F     = 512;
constexpr int NEC   = 512;   // codebook entries

constexpr int   GRID_N = 64;     // fq22 spatial grid
constexpr float GCELL  = 0.25f;  // covers [0,16) x [0,16)
constexpr int   GCAP   = 96;     // max candidates per cell

// ---------------- wave reduce helpers (no atomics) ----------------
__device__ __forceinline__ double wave_reduce_add(double v) {
    #pragma unroll
    for (int off = 32; off; off >>= 1) v += __shfl_xor(v, off);
    return v;
}

// 4-wave block: fixed-order fp64 partial -> pbuf[idx]
__device__ __forceinline__ void block_partial_idx(double dsum, double* pbuf, int idx) {
    __shared__ double wsum[4];
    const int t = threadIdx.x;
    dsum = wave_reduce_add(dsum);
    if ((t & 63) == 0) wsum[t >> 6] = dsum;
    __syncthreads();
    if (t == 0)
        pbuf[idx] = ((wsum[0] + wsum[1]) + wsum[2]) + wsum[3];
}

// ---------------- fused: fq22 grid build (blocks 0-1023) + weight-VQ (blocks 1024-1087) ----------------
__global__ __launch_bounds__(256) void k_prep_wq(
    const float* __restrict__ E3, float* __restrict__ ecb3,
    int* __restrict__ gcnt, short* __restrict__ glist,
    const float* __restrict__ W2, const float* __restrict__ E2,
    float* __restrict__ qW2, double* __restrict__ pwq)
{
    const int t = threadIdx.x;
    if (blockIdx.x >= 1024) {
        // ---------- weight quantization (verbatim round-4 math) ----------
        const int wb = blockIdx.x - 1024;          // 0..63
        __shared__ float Es[NEC][16];
        __shared__ float Cn[NEC];
        for (int i = t; i < 16 * NEC; i += 256) Es[i & (NEC - 1)][i >> 9] = E2[i];
        __syncthreads();
        for (int n = t; n < NEC; n += 256) {
            float c = __fmul_rn(Es[n][0], Es[n][0]);
            #pragma unroll
            for (int j = 1; j < 16; ++j)
                c = __fadd_rn(c, __fmul_rn(Es[n][j], Es[n][j]));
            Cn[n] = c;
        }
        __syncthreads();
        const int idx = wb * 256 + t;              // 16384 vectors
        const int g = idx >> 6, c = idx & 63;
        float v[16];
        #pragma unroll
        for (int k = 0; k < 16; ++k)
            v[k] = W2[(size_t)(2 * g + (k & 1)) * F + 8 * c + (k >> 1)];
        float s[16];
        #pragma unroll
        for (int k = 0; k < 16; ++k) s[k] = __fmul_rn(v[k], v[k]);
        float r[8];
        #pragma unroll
        for (int j = 0; j < 8; ++j) r[j] = __fadd_rn(s[j], s[j + 8]);
        const float Aterm = __fadd_rn(
            __fadd_rn(__fadd_rn(r[0], r[1]), __fadd_rn(r[2], r[3])),
            __fadd_rn(__fadd_rn(r[4], r[5]), __fadd_rn(r[6], r[7])));
        float best = 3.4e38f; int bi = 0;
        for (int n = 0; n < NEC; ++n) {
            float bsum = __fmul_rn(v[0], Es[n][0]);
            #pragma unroll
            for (int k = 1; k < 16; ++k) bsum = fmaf(v[k], Es[n][k], bsum);
            float d = __fadd_rn(__fsub_rn(Aterm, __fadd_rn(bsum, bsum)), Cn[n]);
            if (d < best) { best = d; bi = n; }
        }
        double dsum = 0.0;
        #pragma unroll
        for (int k = 0; k < 16; ++k) {
            float df = __fsub_rn(Es[bi][k], v[k]);
            dsum += (double)df * (double)df;
            qW2[(size_t)(2 * g + (k & 1)) * F + 8 * c + (k >> 1)] = __fadd_rn(v[k], df);
        }
        block_partial_idx(dsum, pwq, wb);
        return;
    }
    // ---------- gridprep (one wave per cell) ----------
    __shared__ float ex[NEC], ey[NEC];
    for (int i = t; i < NEC; i += 256) {   // coalesced stage, once per block
        ex[i] = E3[i];
        ey[i] = E3[NEC + i];
    }
    __syncthreads();
    const int gid = blockIdx.x * 256 + t;
    if (gid < NEC) {   // pack {e0,e1,|e|^2,0} (blocks 0-1)
        float a0 = ex[gid], a1 = ey[gid];
        float cn = __fadd_rn(__fmul_rn(a0, a0), __fmul_rn(a1, a1));
        reinterpret_cast<float4*>(ecb3)[gid] = make_float4(a0, a1, cn, 0.f);
    }
    const int wv = t >> 6, l = t & 63;
    const int cell = blockIdx.x * 4 + wv;          // 4096 cells
    const int cx = cell & (GRID_N - 1), cy = cell >> 6;
    const float x0 = cx * GCELL, x1 = x0 + GCELL;
    const float y0 = cy * GCELL, y1 = y0 + GCELL;
    float mU = 3.4e38f;
    #pragma unroll
    for (int j = 0; j < 8; ++j) {
        const int n = j * 64 + l;
        float exn = ex[n], eyn = ey[n];
        float dxmax = fmaxf(x1 - exn, exn - x0);
        float dymax = fmaxf(y1 - eyn, eyn - y0);
        mU = fminf(mU, dxmax * dxmax + dymax * dymax);
    }
    #pragma unroll
    for (int off = 32; off; off >>= 1) mU = fminf(mU, __shfl_xor(mU, off));
    const float thr = mU + 0.01f;
    int cnt = 0;
    short* lst = glist + (size_t)cell * GCAP;
    #pragma unroll
    for (int j = 0; j < 8; ++j) {
        const int n = j * 64 + l;
        float exn = ex[n], eyn = ey[n];
        float dxmin = fmaxf(fmaxf(x0 - exn, exn - x1), 0.f);
        float dymin = fmaxf(fmaxf(y0 - eyn, eyn - y1), 0.f);
        const bool acc = (dxmin * dxmin + dymin * dymin <= thr);
        unsigned long long mask = __ballot(acc);
        if (acc) {
            int pos = cnt + __popcll(mask & ((1ull << l) - 1ull));
            if (pos < GCAP) lst[pos] = (short)n;
        }
        cnt += __popcll(mask);
    }
    if (l == 0) gcnt[cell] = cnt;
}

// ---- GEMM (NT) emulating BLAS sgemm: per-output sequential-k fma chain within
// ---- KC-panels, panel partials combined in order with fp32 adds (bit-exact).
// ---- 64x64 tile, 4x4/thread, 256 threads, LDS dbuf + reg prefetch,
// ---- XCD-bijective swizzle, 2 blocks/CU (round-18 best-known geometry).
template<bool RELU, bool BN>
__global__ __launch_bounds__(256, 2) void k_gemm_np(
    const float* __restrict__ A, const float* __restrict__ Bw, float* __restrict__ C,
    int M, int N, int K, int KC,
    const float* __restrict__ mu, const float* __restrict__ rs,
    const float* __restrict__ gamma, const float* __restrict__ beta)
{
    __shared__ float As[2][16][68];
    __shared__ float Bs[2][16][68];
    const int t  = threadIdx.x;
    // XCD-bijective swizzle (nwg = 8*gridDim.y, divisible by 8): XCD k owns
    // 8 consecutive A-panels + whole B -> per-XCD L2 reuse.
    const int nwgy = gridDim.y;
    const int bid  = blockIdx.y * 8 + blockIdx.x;
    const int swz  = (bid & 7) * nwgy + (bid >> 3);
    const int bm = (swz >> 3) * 64, bn = (swz & 7) * 64;
    const int tm = (t >> 4) * 4, tn = (t & 15) * 4;
    const int rA = t >> 2;
    const int c4 = (t & 3) * 4;
    const float* Arow = A + (size_t)(bm + rA) * K + c4;
    const float* Brow = Bw + (size_t)(bn + rA) * K + c4;

    float tot[4][4];
    float accp[4][4] = {};
    bool first = true;

    // stage chunk 0
    {
        float4 af = *reinterpret_cast<const float4*>(Arow);
        float4 bf = *reinterpret_cast<const float4*>(Brow);
        float av[4] = {af.x, af.y, af.z, af.w};
        if (BN) {
            #pragma unroll
            for (int u = 0; u < 4; ++u) {
                const int k = c4 + u;
                float d = __fsub_rn(av[u], mu[k]);
                d = __fmul_rn(d, rs[k]);
                d = __fmul_rn(d, gamma[k]);
                av[u] = __fadd_rn(d, beta[k]);
            }
        }
        As[0][c4 + 0][rA] = av[0]; As[0][c4 + 1][rA] = av[1];
        As[0][c4 + 2][rA] = av[2]; As[0][c4 + 3][rA] = av[3];
        Bs[0][c4 + 0][rA] = bf.x;  Bs[0][c4 + 1][rA] = bf.y;
        Bs[0][c4 + 2][rA] = bf.z;  Bs[0][c4 + 3][rA] = bf.w;
    }
    __syncthreads();

    int cur = 0;
    for (int k0 = 0; k0 < K; k0 += 16) {
        const bool has_next = (k0 + 16) < K;
        float4 a_p, b_p;
        if (has_next) {                     // issue next-chunk loads early
            a_p = *reinterpret_cast<const float4*>(Arow + k0 + 16);
            b_p = *reinterpret_cast<const float4*>(Brow + k0 + 16);
        }
        #pragma unroll
        for (int kk = 0; kk < 16; ++kk) {
            float4 a4 = *reinterpret_cast<const float4*>(&As[cur][kk][tm]);
            float4 b4 = *reinterpret_cast<const float4*>(&Bs[cur][kk][tn]);
            float aa[4] = {a4.x, a4.y, a4.z, a4.w};
            float bb[4] = {b4.x, b4.y, b4.z, b4.w};
            #pragma unroll
            for (int i = 0; i < 4; ++i)
                #pragma unroll
                for (int j = 0; j < 4; ++j)
                    accp[i][j] = fmaf(aa[i], bb[j], accp[i][j]);
        }
        if (has_next) {
            float av[4] = {a_p.x, a_p.y, a_p.z, a_p.w};
            if (BN) {
                #pragma unroll
                for (int u = 0; u < 4; ++u) {
                    const int k = k0 + 16 + c4 + u;
                    float d = __fsub_rn(av[u], mu[k]);
                    d = __fmul_rn(d, rs[k]);
                    d = __fmul_rn(d, gamma[k]);
                    av[u] = __fadd_rn(d, beta[k]);
                }
            }
            const int alt = cur ^ 1;
            As[alt][c4 + 0][rA] = av[0]; As[alt][c4 + 1][rA] = av[1];
            As[alt][c4 + 2][rA] = av[2]; As[alt][c4 + 3][rA] = av[3];
            Bs[alt][c4 + 0][rA] = b_p.x; Bs[alt][c4 + 1][rA] = b_p.y;
            Bs[alt][c4 + 2][rA] = b_p.z; Bs[alt][c4 + 3][rA] = b_p.w;
        }
        __syncthreads();                    // single barrier per chunk
        const int kend = k0 + 16;
        if ((kend % KC) == 0 || kend == K) {   // panel boundary: fold partial
            #pragma unroll
            for (int i = 0; i < 4; ++i)
                #pragma unroll
                for (int j = 0; j < 4; ++j) {
                    tot[i][j] = first ? accp[i][j] : __fadd_rn(tot[i][j], accp[i][j]);
                    accp[i][j] = 0.f;
                }
            first = false;
        }
        cur ^= 1;
    }
    #pragma unroll
    for (int i = 0; i < 4; ++i) {
        float r0 = RELU ? fmaxf(tot[i][0], 0.f) : tot[i][0];
        float r1 = RELU ? fmaxf(tot[i][1], 0.f) : tot[i][1];
        float r2 = RELU ? fmaxf(tot[i][2], 0.f) : tot[i][2];
        float r3 = RELU ? fmaxf(tot[i][3], 0.f) : tot[i][3];
        float4 r = make_float4(r0, r1, r2, r3);
        *reinterpret_cast<float4*>(&C[(size_t)(bm + tm + i) * N + bn + tn]) = r;
    }
}

// ---------------- fq21: dim-8 VQ, LDS codebook, index-only tracking ----------------
__global__ __launch_bounds__(256) void k_fq21_np(
    const float* __restrict__ h, const float* __restrict__ E,
    float* __restrict__ qx, double* __restrict__ pbuf)
{
    __shared__ float Es[NEC][8];
    __shared__ float Cn[NEC];
    const int t = threadIdx.x;
    for (int i = t; i < 8 * NEC; i += 256) Es[i & (NEC - 1)][i >> 9] = E[i];
    __syncthreads();
    for (int n = t; n < NEC; n += 256) {
        float c = __fmul_rn(Es[n][0], Es[n][0]);
        #pragma unroll
        for (int j = 1; j < 8; ++j)
            c = __fadd_rn(c, __fmul_rn(Es[n][j], Es[n][j]));
        Cn[n] = c;
    }
    __syncthreads();
    const int idx = blockIdx.x * 256 + t;
    const int b = idx >> 6, c = idx & 63;
    const float* hb = h + (size_t)b * F + c;
    float v[8];
    #pragma unroll
    for (int j = 0; j < 8; ++j) v[j] = hb[j * 64];
    float s[8];
    #pragma unroll
    for (int j = 0; j < 8; ++j) s[j] = __fmul_rn(v[j], v[j]);
    // numpy pairwise n=8: ((s0+s1)+(s2+s3)) + ((s4+s5)+(s6+s7))
    const float Aterm = __fadd_rn(
        __fadd_rn(__fadd_rn(s[0], s[1]), __fadd_rn(s[2], s[3])),
        __fadd_rn(__fadd_rn(s[4], s[5]), __fadd_rn(s[6], s[7])));
    float best = 3.4e38f; int bi = 0;
    for (int n = 0; n < NEC; ++n) {
        float4 e0 = *reinterpret_cast<const float4*>(&Es[n][0]);
        float4 e1 = *reinterpret_cast<const float4*>(&Es[n][4]);
        float bsum = __fmul_rn(v[0], e0.x);
        bsum = fmaf(v[1], e0.y, bsum);
        bsum = fmaf(v[2], e0.z, bsum);
        bsum = fmaf(v[3], e0.w, bsum);
        bsum = fmaf(v[4], e1.x, bsum);
        bsum = fmaf(v[5], e1.y, bsum);
        bsum = fmaf(v[6], e1.z, bsum);
        bsum = fmaf(v[7], e1.w, bsum);
        float d = __fadd_rn(__fsub_rn(Aterm, __fadd_rn(bsum, bsum)), Cn[n]);
        if (d < best) { best = d; bi = n; }
    }
    float4 q0 = *reinterpret_cast<const float4*>(&Es[bi][0]);
    float4 q1 = *reinterpret_cast<const float4*>(&Es[bi][4]);
    float bq[8] = {q0.x, q0.y, q0.z, q0.w, q1.x, q1.y, q1.z, q1.w};
    double dsum = 0.0;
    float* qb = qx + (size_t)b * F + c;
    #pragma unroll
    for (int j = 0; j < 8; ++j) {
        float df = __fsub_rn(bq[j], v[j]);        // fl(q - x)
        dsum += (double)df * (double)df;
        qb[j * 64] = __fadd_rn(v[j], df);         // fl(x + fl(q - x))
    }
    block_partial_idx(dsum, pbuf, blockIdx.x);
}

// ---------------- transpose qx [4096][512] -> qxT [512][4096] ----------------
__global__ __launch_bounds__(256) void k_transpose(
    const float* __restrict__ qx, float* __restrict__ qxT)
{
    __shared__ float tile[64][65];
    const int t = threadIdx.x;
    const int bx = blockIdx.x * 64;   // f base
    const int by = blockIdx.y * 64;   // b base
    const int r = t >> 4, c4 = (t & 15) * 4;
    #pragma unroll
    for (int s = 0; s < 4; ++s) {
        float4 v = *reinterpret_cast<const float4*>(&qx[(size_t)(by + r + s * 16) * F + bx + c4]);
        tile[r + s * 16][c4 + 0] = v.x; tile[r + s * 16][c4 + 1] = v.y;
        tile[r + s * 16][c4 + 2] = v.z; tile[r + s * 16][c4 + 3] = v.w;
    }
    __syncthreads();
    const int fo = t >> 4, b4 = (t & 15) * 4;
    #pragma unroll
    for (int s = 0; s < 4; ++s) {
        float4 v;
        v.x = tile[b4 + 0][fo + s * 16];
        v.y = tile[b4 + 1][fo + s * 16];
        v.z = tile[b4 + 2][fo + s * 16];
        v.w = tile[b4 + 3][fo + s * 16];
        *reinterpret_cast<float4*>(&qxT[(size_t)(bx + fo + s * 16) * BATCH + by + b4]) = v;
    }
}

// ---------------- BN stats: numpy sequential fp32 on contiguous qxT rows ----------------
// 32 blocks x 16 ACTIVE lanes (one column each, chains unchanged): spreads the
// uncoalesced TA request stream over 32 CUs and 4x's aggregate in-flight loads.
__global__ __launch_bounds__(64) void k_bn(
    const float* __restrict__ qxT, float* __restrict__ mu, float* __restrict__ rs)
{
    const int t = threadIdx.x;
    if (t >= 16) return;                       // 16 active lanes per wave
    const int f = blockIdx.x * 16 + t;         // 32 blocks x 16 = 512 cols
    const float4* rp = reinterpret_cast<const float4*>(qxT + (size_t)f * BATCH);

    float4 b0[4], b1[4], b2[4], b3[4], b4[4], b5[4], b6[4], b7[4];

#define BN_LD(B, c)                                                          \
    { _Pragma("unroll") for (int q = 0; q < 4; ++q) B[q] = rp[(c) * 4 + q]; }
#define BN_SUM(B)                                                            \
    { _Pragma("unroll") for (int q = 0; q < 4; ++q) {                        \
        acc = __fadd_rn(acc, B[q].x); acc = __fadd_rn(acc, B[q].y);          \
        acc = __fadd_rn(acc, B[q].z); acc = __fadd_rn(acc, B[q].w); } }
#define BN_VAR(B)                                                            \
    { _Pragma("unroll") for (int q = 0; q < 4; ++q) { float d_;              \
        d_ = __fsub_rn(B[q].x, m); acc2 = __fadd_rn(acc2, __fmul_rn(d_, d_));\
        d_ = __fsub_rn(B[q].y, m); acc2 = __fadd_rn(acc2, __fmul_rn(d_, d_));\
        d_ = __fsub_rn(B[q].z, m); acc2 = __fadd_rn(acc2, __fmul_rn(d_, d_));\
        d_ = __fsub_rn(B[q].w, m); acc2 = __fadd_rn(acc2, __fmul_rn(d_, d_)); } }

    // ---------- pass 1: mean (chunks of 16 rows; 256 chunks) ----------
    float acc = 0.f;
    BN_LD(b0, 0) BN_LD(b1, 1) BN_LD(b2, 2) BN_LD(b3, 3)
    BN_LD(b4, 4) BN_LD(b5, 5) BN_LD(b6, 6)
    for (int g = 0; g < 31; ++g) {
        BN_LD(b7, 8 * g + 7)  BN_SUM(b0)
        BN_LD(b0, 8 * g + 8)  BN_SUM(b1)
        BN_LD(b1, 8 * g + 9)  BN_SUM(b2)
        BN_LD(b2, 8 * g + 10) BN_SUM(b3)
        BN_LD(b3, 8 * g + 11) BN_SUM(b4)
        BN_LD(b4, 8 * g + 12) BN_SUM(b5)
        BN_LD(b5, 8 * g + 13) BN_SUM(b6)
        BN_LD(b6, 8 * g + 14) BN_SUM(b7)
    }
    BN_LD(b7, 255)
    BN_SUM(b0) BN_SUM(b1) BN_SUM(b2) BN_SUM(b3)
    BN_SUM(b4) BN_SUM(b5) BN_SUM(b6) BN_SUM(b7)
    const float m = __fmul_rn(acc, 1.f / 4096.f);   // exact (/2^12)

    // ---------- pass 2: biased var, numpy order ----------
    float acc2 = 0.f;
    BN_LD(b0, 0) BN_LD(b1, 1) BN_LD(b2, 2) BN_LD(b3, 3)
    BN_LD(b4, 4) BN_LD(b5, 5) BN_LD(b6, 6)
    for (int g = 0; g < 31; ++g) {
        BN_LD(b7, 8 * g + 7)  BN_VAR(b0)
        BN_LD(b0, 8 * g + 8)  BN_VAR(b1)
        BN_LD(b1, 8 * g + 9)  BN_VAR(b2)
        BN_LD(b2, 8 * g + 10) BN_VAR(b3)
        BN_LD(b3, 8 * g + 11) BN_VAR(b4)
        BN_LD(b4, 8 * g + 12) BN_VAR(b5)
        BN_LD(b5, 8 * g + 13) BN_VAR(b6)
        BN_LD(b6, 8 * g + 14) BN_VAR(b7)
    }
    BN_LD(b7, 255)
    BN_VAR(b0) BN_VAR(b1) BN_VAR(b2) BN_VAR(b3)
    BN_VAR(b4) BN_VAR(b5) BN_VAR(b6) BN_VAR(b7)
#undef BN_LD
#undef BN_SUM
#undef BN_VAR
    float var = __fmul_rn(acc2, 1.f / 4096.f);
    float w = __fadd_rn(var, 1e-5f);
    mu[f] = m;
    rs[f] = __fdiv_rn(1.0f, __fsqrt_rn(w));
}

// ---------------- fq22: dim-2 VQ via spatial-grid pruned search ----------------
__global__ __launch_bounds__(256) void k_fq22_np(
    const float* __restrict__ h2, const float* __restrict__ ecb3,
    const int* __restrict__ gcnt, const short* __restrict__ glist,
    float* __restrict__ qx2, double* __restrict__ pbuf)
{
    __shared__ float4 EsL[NEC];
    const int t = threadIdx.x;
    for (int n = t; n < NEC; n += 256)
        EsL[n] = reinterpret_cast<const float4*>(ecb3)[n];
    __syncthreads();
    const int b = blockIdx.x;
    const float v0 = h2[(size_t)b * F + t];         // >= 0 (relu)
    const float v1 = h2[(size_t)b * F + 256 + t];   // >= 0
    const float Aterm = __fadd_rn(__fmul_rn(v0, v0), __fmul_rn(v1, v1));
    float best = 3.4e38f; int bi = 0;
    const bool inbox = (v0 < 16.f) && (v1 < 16.f);
    int cx = (int)(v0 * 4.f), cy = (int)(v1 * 4.f);
    int cell = (cy << 6) + cx;
    int cnt = inbox ? gcnt[cell] : (NEC + 1);       // out-of-box -> full scan
    if (cnt <= GCAP) {
        const short* lst = glist + (size_t)cell * GCAP;
        int i = 0;
        const int cnt4 = cnt & ~3;
        for (; i < cnt4; i += 4) {                   // one 8B gather per 4 ids
            ushort4 ids = *reinterpret_cast<const ushort4*>(lst + i);
            float4 ea = EsL[ids.x];
            float4 eb = EsL[ids.y];
            float4 ec = EsL[ids.z];
            float4 ed = EsL[ids.w];
            float ba = fmaf(v1, ea.y, __fmul_rn(v0, ea.x));
            float da = __fadd_rn(__fsub_rn(Aterm, __fadd_rn(ba, ba)), ea.z);
            if (da < best) { best = da; bi = ids.x; }
            float bb = fmaf(v1, eb.y, __fmul_rn(v0, eb.x));
            float db = __fadd_rn(__fsub_rn(Aterm, __fadd_rn(bb, bb)), eb.z);
            if (db < best) { best = db; bi = ids.y; }
            float bc = fmaf(v1, ec.y, __fmul_rn(v0, ec.x));
            float dc = __fadd_rn(__fsub_rn(Aterm, __fadd_rn(bc, bc)), ec.z);
            if (dc < best) { best = dc; bi = ids.z; }
            float bd = fmaf(v1, ed.y, __fmul_rn(v0, ed.x));
            float dd = __fadd_rn(__fsub_rn(Aterm, __fadd_rn(bd, bd)), ed.z);
            if (dd < best) { best = dd; bi = ids.w; }
        }
        for (; i < cnt; ++i) {
            int id = lst[i];
            float4 e = EsL[id];
            float bsum = fmaf(v1, e.y, __fmul_rn(v0, e.x));
            float d = __fadd_rn(__fsub_rn(Aterm, __fadd_rn(bsum, bsum)), e.z);
            if (d < best) { best = d; bi = id; }
        }
    } else {
        for (int n = 0; n < NEC; ++n) {
            float4 e = EsL[n];
            float bsum = fmaf(v1, e.y, __fmul_rn(v0, e.x));
            float d = __fadd_rn(__fsub_rn(Aterm, __fadd_rn(bsum, bsum)), e.z);
            if (d < best) { best = d; bi = n; }
        }
    }
    float4 eb = EsL[bi];
    float d0 = __fsub_rn(eb.x, v0), d1 = __fsub_rn(eb.y, v1);
    qx2[(size_t)b * F + t]       = __fadd_rn(v0, d0);
    qx2[(size_t)b * F + 256 + t] = __fadd_rn(v1, d1);
    block_partial_idx((double)d0 * d0 + (double)d1 * d1, pbuf, blockIdx.x);
}

// ---------------- final thin GEMM + fused diff reduction ----------------
// blocks 0..1023: out[b,o] = sum_i qx2[b,i] * W3[o,i]; last block: reduce diffs.
__global__ __launch_bounds__(256) void k_gemm3(
    const float* __restrict__ qx2, const float* __restrict__ W3, float* __restrict__ out,
    const double* __restrict__ p21, const double* __restrict__ pwq,
    const double* __restrict__ p22)
{
    const int t = threadIdx.x;
    if (blockIdx.x == gridDim.x - 1) {
        __shared__ double sd[256];
        __shared__ double res[2];
        // --- p21 (1024) ---
        double s = 0.0;
        for (int i = t; i < 1024; i += 256) s += p21[i];
        sd[t] = s; __syncthreads();
        for (int o = 128; o; o >>= 1) { if (t < o) sd[t] += sd[t + o]; __syncthreads(); }
        if (t == 0) res[0] = sd[0];
        __syncthreads();
        // --- pwq (64) ---
        s = (t < 64) ? pwq[t] : 0.0;
        sd[t] = s; __syncthreads();
        for (int o = 128; o; o >>= 1) { if (t < o) sd[t] += sd[t + o]; __syncthreads(); }
        if (t == 0) res[1] = sd[0];
        __syncthreads();
        // --- p22 (4096) ---
        s = 0.0;
        for (int i = t; i < 4096; i += 256) s += p22[i];
        sd[t] = s; __syncthreads();
        for (int o = 128; o; o >>= 1) { if (t < o) sd[t] += sd[t + o]; __syncthreads(); }
        if (t == 0) {
            double d21 = res[0] * (1.0 / 2097152.0);   // 4096*64*8
            double dq  = res[1] * (1.0 / 262144.0);    // 256*64*16
            double d22 = sd[0]  * (1.0 / 2097152.0);   // 4096*256*2
            out[BATCH * 10] = (float)((d21 + d22) + dq);
        }
        return;
    }
    __shared__ float Ws[10 * F];
    for (int i = t; i < 10 * F; i += 256) Ws[i] = W3[i];
    __syncthreads();
    const int w = t >> 6, l = t & 63;
    const int b = blockIdx.x * 4 + w;
    const float* xb = qx2 + (size_t)b * F;
    double acc[10] = {};
    for (int i = l; i < F; i += 64) {
        double xv = (double)xb[i];
        #pragma unroll
        for (int o = 0; o < 10; ++o) acc[o] = fma(xv, (double)Ws[o * F + i], acc[o]);
    }
    #pragma unroll
    for (int o = 0; o < 10; ++o) {
        double a = wave_reduce_add(acc[o]);
        if (l == 0) out[(size_t)b * 10 + o] = (float)a;
    }
}

extern "C" void kernel_launch(void* const* d_in, const int* in_sizes, int n_in,
                              void* d_out, int out_size, void* d_ws, size_t ws_size,
                              hipStream_t stream)
{
    const float* x     = (const float*)d_in[0];
    const float* W1    = (const float*)d_in[1];
    const float* W2    = (const float*)d_in[2];
    const float* W3    = (const float*)d_in[3];
    const float* gamma = (const float*)d_in[4];
    const float* beta  = (const float*)d_in[5];
    const float* E1    = (const float*)d_in[6];   // [8,512]
    const float* E2    = (const float*)d_in[7];   // [16,512]
    const float* E3    = (const float*)d_in[8];   // [2,512]
    float* out = (float*)d_out;

    const int KC = 512;   // confirmed round 4 (BLIS/zen single-panel for K=512)

    char* ws = (char*)d_ws;
    float*  hf    = (float*)ws;                                 // 8 MB (h, then h2)
    float*  qxf   = (float*)(ws + (size_t) 8 * 1024 * 1024);    // 8 MB (qx, then qx2)
    float*  qW2f  = (float*)(ws + (size_t)16 * 1024 * 1024);    // 1 MB
    float*  muf   = (float*)(ws + (size_t)17 * 1024 * 1024);    // 512 f32
    float*  rsf   = muf + F;                                    // 512 f32
    float*  ecb3  = (float*)(ws + (size_t)17 * 1024 * 1024 + 8192);    // 512*4 f32
    int*    gcnt  = (int*)(ws + (size_t)18 * 1024 * 1024);      // 4096 int
    short*  glist = (short*)(ws + (size_t)18 * 1024 * 1024 + 16384);   // 4096*96 i16
    double* p21   = (double*)(ws + (size_t)19 * 1024 * 1024);   // 1024 f64
    double* pwq   = p21 + 1024;                                 // 64 f64
    double* p22   = pwq + 64;                                   // 4096 f64
    float*  qxT   = (float*)(ws + (size_t)20 * 1024 * 1024);    // 8 MB [512][4096]

    // gridprep (blocks 0-1023) + weight-VQ (blocks 1024-1087), one launch
    k_prep_wq<<<1088, 256, 0, stream>>>(E3, ecb3, gcnt, glist, W2, E2, qW2f, pwq);
    // h = relu(x @ W1^T)  — sgemm emulation, KC panels (784 = 512 + 272)
    k_gemm_np<true, false><<<dim3(F / 64, BATCH / 64), 256, 0, stream>>>(
        x, W1, hf, BATCH, F, D_IN, KC, nullptr, nullptr, nullptr, nullptr);
    // fq21 -> qx
    k_fq21_np<<<BATCH * 64 / 256, 256, 0, stream>>>(hf, E1, qxf, p21);
    // qx -> qxT (for contiguous column reads in k_bn)
    k_transpose<<<dim3(F / 64, BATCH / 64), 256, 0, stream>>>(qxf, qxT);
    // BN stats (sequential fp32, numpy order; 32-block/16-lane float4 pipeline)
    k_bn<<<32, 64, 0, stream>>>(qxT, muf, rsf);
    // h2 = relu(bn(qx) @ qW2^T) — K=512 = single panel -> pure sequential fma
    k_gemm_np<true, true><<<dim3(F / 64, BATCH / 64), 256, 0, stream>>>(
        qxf, qW2f, hf, BATCH, F, F, KC, muf, rsf, gamma, beta);
    // fq22 -> qx2 (grid-pruned, vectorized id gather)
    k_fq22_np<<<BATCH, 256, 0, stream>>>(hf, ecb3, gcnt, glist, qxf, p22);
    // out = qx2 @ W3^T (+ fused diff reduce in the extra block)
    k_gemm3<<<BATCH / 4 + 1, 256, 0, stream>>>(qxf, W3, out, p21, pwq, p22);
}